// Round 1
// baseline (85.124 us; speedup 1.0000x reference)
//
#include <hip/hip_runtime.h>
#include <cmath>

#define NROWS 2048          // B*S = 4*512
#define MATSZ (NROWS * 128) // 262144 floats per projection matrix output

// ---------------- Kernel 1: fused QKV projection + quantum layer -------------
// q/k/v[n,e] = sum_f x[n,f] * W[e,f]; then per head (8 cols): theta = val+qsum,
// c = cos(theta), outputs are parity-chain prefix products of c.
// Writes qkv in [m][b*16+h][s][8] layout (m=0:q, 1:k, 2:v).
// grid: 128 blocks (16 rows each), block: 384 threads (one W row per thread).
__global__ __launch_bounds__(384) void k_qkv_quantum(
    const float* __restrict__ x, const float* __restrict__ Wq,
    const float* __restrict__ Wk, const float* __restrict__ Wv,
    const float* __restrict__ qp, float* __restrict__ qkv) {
  __shared__ __align__(16) float xs[16][128];
  __shared__ __align__(16) float th[16][384];
  const int t = threadIdx.x;
  const int row0 = blockIdx.x << 4;
  {
    const float4* xg = (const float4*)(x + (size_t)row0 * 128);
    float4* xsv = (float4*)&xs[0][0];
    for (int i = t; i < 16 * 32; i += 384) xsv[i] = xg[i];
  }
  __syncthreads();
  // thread owns fused output column e = t in [0,384): m = t>>7, col = t&127
  const int m = t >> 7;
  const int col = t & 127;
  const float* W = (m == 0) ? Wq : (m == 1) ? Wk : Wv;
  float4 w[32];
  {
    const float4* wr = (const float4*)(W + (size_t)col * 128);
#pragma unroll
    for (int f = 0; f < 32; ++f) w[f] = wr[f];
  }
  for (int r = 0; r < 16; ++r) {
    const float4* xr = (const float4*)&xs[r][0];
    float a = 0.f;
#pragma unroll
    for (int f = 0; f < 32; ++f) {
      float4 xv = xr[f];  // broadcast LDS read (all lanes same addr) — free
      a = fmaf(xv.x, w[f].x, a);
      a = fmaf(xv.y, w[f].y, a);
      a = fmaf(xv.z, w[f].z, a);
      a = fmaf(xv.w, w[f].w, a);
    }
    th[r][t] = a;
  }
  __syncthreads();
  float qsum[8];
#pragma unroll
  for (int j = 0; j < 8; ++j) qsum[j] = qp[j] + qp[8 + j];
  // 768 (row, matrix*head) tasks; 2 per thread
  for (int task = t; task < 768; task += 384) {
    const int r = task / 48;
    const int g = task % 48;
    const int mm = g >> 4;
    const int h = g & 15;
    float c[8];
#pragma unroll
    for (int j = 0; j < 8; ++j)
      c[j] = cosf(th[r][(mm << 7) + (h << 3) + j] + qsum[j]);
    // parity-chain prefix products (closed form of 2 CNOT ladders + <Z_w>)
    float o[8];
    o[0] = c[0];        o[1] = c[1];
    o[2] = o[0] * c[2]; o[3] = o[1] * c[3];
    o[4] = o[2] * c[4]; o[5] = o[3] * c[5];
    o[6] = o[4] * c[6]; o[7] = o[5] * c[7];
    const int row = row0 + r;
    const int b = row >> 9;
    const int s = row & 511;
    float* dst = qkv + (size_t)mm * MATSZ + ((size_t)((b << 4) + h) * 512 + s) * 8;
    ((float4*)dst)[0] = make_float4(o[0], o[1], o[2], o[3]);
    ((float4*)dst)[1] = make_float4(o[4], o[5], o[6], o[7]);
  }
}

// ---------------- Kernel 2: attention per (b,h), d=8 -------------------------
// |score| <= 8/sqrt(8) = 2.83 (inputs are products of cosines, |.|<=1), so
// softmax needs no max subtraction: p = exp(s), normalize by sum at the end.
// grid: 64 bh * 8 q-tiles = 512 blocks; block 256 threads.
// thread = (q-row within tile of 64) x (quarter of k-range); 4-lane combine.
__global__ __launch_bounds__(256) void k_attn(
    const float* __restrict__ qkv, float* __restrict__ aout) {
  __shared__ __align__(16) float ks[512][8];
  __shared__ __align__(16) float vs[512][8];
  const int bh = blockIdx.x >> 3;
  const int tile = blockIdx.x & 7;
  const float* qb = qkv + (size_t)bh * 4096;
  const float* kb = qkv + (size_t)MATSZ + (size_t)bh * 4096;
  const float* vb = qkv + 2 * (size_t)MATSZ + (size_t)bh * 4096;
  const int t = threadIdx.x;
  {
    const float4* kg = (const float4*)kb;
    const float4* vg = (const float4*)vb;
    float4* ksv = (float4*)&ks[0][0];
    float4* vsv = (float4*)&vs[0][0];
    for (int i = t; i < 1024; i += 256) { ksv[i] = kg[i]; vsv[i] = vg[i]; }
  }
  __syncthreads();
  const int row = (tile << 6) + (t >> 2);
  const int qtr = t & 3;
  const float scale = 0.35355339059327373f; // 1/sqrt(8)
  float4 qa = ((const float4*)(qb + (size_t)row * 8))[0];
  float4 qc = ((const float4*)(qb + (size_t)row * 8))[1];
  qa.x *= scale; qa.y *= scale; qa.z *= scale; qa.w *= scale;
  qc.x *= scale; qc.y *= scale; qc.z *= scale; qc.w *= scale;
  float l = 0.f;
  float acc[8];
#pragma unroll
  for (int j = 0; j < 8; ++j) acc[j] = 0.f;
  const int kk0 = qtr << 7;
  for (int k = kk0; k < kk0 + 128; ++k) {
    float4 kx = ((const float4*)&ks[k][0])[0];
    float4 ky = ((const float4*)&ks[k][0])[1];
    float s = qa.x * kx.x + qa.y * kx.y + qa.z * kx.z + qa.w * kx.w +
              qc.x * ky.x + qc.y * ky.y + qc.z * ky.z + qc.w * ky.w;
    float p = __expf(s);
    float4 vx = ((const float4*)&vs[k][0])[0];
    float4 vy = ((const float4*)&vs[k][0])[1];
    l += p;
    acc[0] = fmaf(p, vx.x, acc[0]);
    acc[1] = fmaf(p, vx.y, acc[1]);
    acc[2] = fmaf(p, vx.z, acc[2]);
    acc[3] = fmaf(p, vx.w, acc[3]);
    acc[4] = fmaf(p, vy.x, acc[4]);
    acc[5] = fmaf(p, vy.y, acc[5]);
    acc[6] = fmaf(p, vy.z, acc[6]);
    acc[7] = fmaf(p, vy.w, acc[7]);
  }
  // combine the 4 k-quarters (lanes t^1, t^2 within the wave)
  l += __shfl_xor(l, 1);
  l += __shfl_xor(l, 2);
#pragma unroll
  for (int j = 0; j < 8; ++j) {
    acc[j] += __shfl_xor(acc[j], 1);
    acc[j] += __shfl_xor(acc[j], 2);
  }
  if (qtr == 0) {
    const float inv = 1.f / l;
    const int b = bh >> 4;
    const int h = bh & 15;
    float* dst = aout + (size_t)((b << 9) + row) * 128 + (h << 3);
    ((float4*)dst)[0] = make_float4(acc[0] * inv, acc[1] * inv, acc[2] * inv, acc[3] * inv);
    ((float4*)dst)[1] = make_float4(acc[4] * inv, acc[5] * inv, acc[6] * inv, acc[7] * inv);
  }
}

// ---------------- Kernel 3: output projection y = a @ Wo^T -------------------
// grid: 128 blocks (16 rows), block 256 threads (Wo row in regs, 2 threads/col)
__global__ __launch_bounds__(256) void k_outproj(
    const float* __restrict__ a, const float* __restrict__ Wo,
    float* __restrict__ y) {
  __shared__ __align__(16) float as_[16][128];
  const int t = threadIdx.x;
  const int row0 = blockIdx.x << 4;
  {
    const float4* ag = (const float4*)(a + (size_t)row0 * 128);
    float4* asv = (float4*)&as_[0][0];
    for (int i = t; i < 512; i += 256) asv[i] = ag[i];
  }
  __syncthreads();
  const int e = t & 127;
  const int r0 = t >> 7;
  float4 w[32];
  const float4* wr = (const float4*)(Wo + (size_t)e * 128);
#pragma unroll
  for (int f = 0; f < 32; ++f) w[f] = wr[f];
  for (int r = r0; r < 16; r += 2) {
    const float4* ar = (const float4*)&as_[r][0];
    float acc = 0.f;
#pragma unroll
    for (int f = 0; f < 32; ++f) {
      float4 av = ar[f];  // broadcast LDS read
      acc = fmaf(av.x, w[f].x, acc);
      acc = fmaf(av.y, w[f].y, acc);
      acc = fmaf(av.z, w[f].z, acc);
      acc = fmaf(av.w, w[f].w, acc);
    }
    y[(size_t)(row0 + r) * 128 + e] = acc;
  }
}

extern "C" void kernel_launch(void* const* d_in, const int* in_sizes, int n_in,
                              void* d_out, int out_size, void* d_ws, size_t ws_size,
                              hipStream_t stream) {
  const float* x  = (const float*)d_in[0];
  const float* Wq = (const float*)d_in[1];
  const float* Wk = (const float*)d_in[2];
  const float* Wv = (const float*)d_in[3];
  const float* Wo = (const float*)d_in[4];
  const float* qp = (const float*)d_in[5];
  float* out = (float*)d_out;

  float* qkv  = (float*)d_ws;            // 3 * MATSZ floats (3 MB)
  float* aout = qkv + 3 * (size_t)MATSZ; // MATSZ floats (1 MB)

  hipLaunchKernelGGL(k_qkv_quantum, dim3(128), dim3(384), 0, stream,
                     x, Wq, Wk, Wv, qp, qkv);
  hipLaunchKernelGGL(k_attn, dim3(512), dim3(256), 0, stream, qkv, aout);
  hipLaunchKernelGGL(k_outproj, dim3(128), dim3(256), 0, stream, aout, Wo, out);
}